// Round 1
// baseline (7414.895 us; speedup 1.0000x reference)
//
#include <hip/hip_runtime.h>

typedef __attribute__((ext_vector_type(8))) short short8;
typedef __attribute__((ext_vector_type(4))) float f32x4;

#define MFMA(a,b,c) __builtin_amdgcn_mfma_f32_16x16x32_bf16(a,b,c,0,0,0)

// Problem dims
#define S_LEN 128
#define IN_D  8
#define HID   512
#define NL    3

// ws layout (bytes)
#define OFF_WHH 0                      // [3][96][16][64][8] bf16 = 4,718,592
#define OFF_WIH (4718592)              // [3][96][64][8] bf16    =   294,912
#define OFF_BRZ (4718592 + 294912)     // [3][1024] f32          =    12,288
#define OFF_BNI (OFF_BRZ + 12288)      // [3][512] f32           =     6,144
#define OFF_BNH (OFF_BNI + 6144)       // [3][512] f32           =     6,144

__device__ __forceinline__ unsigned short f2bf(float f){
  unsigned u = __float_as_uint(f);
  u += 0x7FFFu + ((u >> 16) & 1u);     // round-to-nearest-even
  return (unsigned short)(u >> 16);
}

// Pack Whh [3][1536][512] f32 -> bf16 MFMA B-fragment order:
// idx = (((l*96+nt)*16+kk)*64+lane)*8 + j ; value = Whh[l][nt*16+(lane&15)][kk*32+(lane>>4)*8+j]
__global__ void prep_whh(const float* __restrict__ Whh, unsigned short* __restrict__ Wp){
  int gid = blockIdx.x * 256 + threadIdx.x;     // 294912 total
  int lane = gid & 63;
  int r = gid >> 6;
  int kk = r & 15; r >>= 4;
  int nt = r % 96;
  int l  = r / 96;
  int n  = nt * 16 + (lane & 15);
  int k0 = kk * 32 + (lane >> 4) * 8;
  const float* src = Whh + ((size_t)l * 1536 + n) * 512 + k0;
  unsigned short t[8];
#pragma unroll
  for (int j = 0; j < 8; ++j) t[j] = f2bf(src[j]);
  uint4 v;
  v.x = t[0] | ((unsigned)t[1] << 16);
  v.y = t[2] | ((unsigned)t[3] << 16);
  v.z = t[4] | ((unsigned)t[5] << 16);
  v.w = t[6] | ((unsigned)t[7] << 16);
  *(uint4*)(Wp + (size_t)gid * 8) = v;
}

// Pack Wih [3][1536][8] -> zero-padded (K=8 of 32) B-fragments: only lanes 0..15 nonzero
__global__ void prep_wih(const float* __restrict__ Wih, unsigned short* __restrict__ Wip){
  int gid = blockIdx.x * 256 + threadIdx.x;     // 18432 total
  int lane = gid & 63;
  int r = gid >> 6;
  int nt = r % 96;
  int l  = r / 96;
  unsigned short t[8] = {0,0,0,0,0,0,0,0};
  if ((lane >> 4) == 0){
    int n = nt * 16 + (lane & 15);
    const float* src = Wih + ((size_t)l * 1536 + n) * 8;
#pragma unroll
    for (int j = 0; j < 8; ++j) t[j] = f2bf(src[j]);
  }
  uint4 v;
  v.x = t[0] | ((unsigned)t[1] << 16);
  v.y = t[2] | ((unsigned)t[3] << 16);
  v.z = t[4] | ((unsigned)t[5] << 16);
  v.w = t[6] | ((unsigned)t[7] << 16);
  *(uint4*)(Wip + (size_t)gid * 8) = v;
}

// brz = bih+bhh for r,z columns; bni = bih_n; bnh = bhh_n (n-gate must keep them split: n = tanh(i_n + r*h_n))
__global__ void prep_bias(const float* __restrict__ bih, const float* __restrict__ bhh,
                          float* __restrict__ brz, float* __restrict__ bni, float* __restrict__ bnh){
  int gid = blockIdx.x * 256 + threadIdx.x;     // 4608 total
  int c = gid % 1536;
  int l = gid / 1536;
  float bi = bih[gid], bh = bhh[gid];
  if (c < 1024) brz[l * 1024 + c] = bi + bh;
  else { bni[l * 512 + (c - 1024)] = bi; bnh[l * 512 + (c - 1024)] = bh; }
}

// Main: 128 blocks x 1024 threads. Block owns batch rows [b0, b0+32).
// Per cell: 16 waves x 2 passes; each pass computes 16 output columns' r/z/n preacts via MFMA
// (A = h rows from LDS bf16, B = packed Whh frags from global/L2), then gates in registers.
// h: fp32 master (single, per-wave-column-exclusive) + bf16 double buffer (one barrier/cell).
__global__ __launch_bounds__(1024, 1) void gru_main(
    const float* __restrict__ x,
    const unsigned short* __restrict__ Wp,
    const unsigned short* __restrict__ Wip,
    const float* __restrict__ brz,
    const float* __restrict__ bni,
    const float* __restrict__ bnh,
    float* __restrict__ out)
{
  __shared__ __align__(16) float hF[32 * 528];              // fp32 h, row stride 528
  __shared__ __align__(16) unsigned short hB[2][32 * 536];  // bf16 h, row stride 536 (16B aligned, ~conflict-free)
  __shared__ __align__(16) unsigned short xpack[1024];      // x_t in A-fragment layout [2 m][64 lane][8]

  const int tid  = threadIdx.x;
  const int wv   = tid >> 6;
  const int lane = tid & 63;
  const int l15  = lane & 15;
  const int l4   = lane >> 4;
  const int b0   = blockIdx.x * 32;

  for (int i = tid; i < 32 * 528; i += 1024) hF[i] = 0.f;
  for (int i = tid; i < 32 * 536; i += 1024){ hB[0][i] = 0; hB[1][i] = 0; }
  __syncthreads();

  // xpack writer mapping: tid = (m*64+lane)*8 + j
  const int xm = tid >> 9, xl = (tid >> 3) & 63, xj = tid & 7;
  const size_t xbase = ((size_t)(b0 + xm * 16 + (xl & 15))) * (S_LEN * IN_D) + xj;
  const int xvalid = (xl < 16);

  const int aoff0 = l15 * 536 + l4 * 8;          // A-frag m=0 (rows 0..15)
  const int aoff1 = aoff0 + 16 * 536;            // A-frag m=1 (rows 16..31)

  int cur = 0;
  for (int t = 0; t < S_LEN; ++t){
    { // stage x_t fragment (shared by all 3 layers)
      float xv = xvalid ? x[xbase + (size_t)t * IN_D] : 0.f;
      xpack[tid] = f2bf(xv);
    }
    __syncthreads();

    for (int l = 0; l < NL; ++l){
#pragma unroll
      for (int p = 0; p < 2; ++p){
        const int cb  = wv * 32 + p * 16;        // output column base (0..511)
        const int ntR = cb >> 4;                 // N-tile index within gate third (0..31)
        const int col = cb + l15;

        const float vR  = brz[l * 1024 + col];
        const float vZ  = brz[l * 1024 + 512 + col];
        const float vNi = bni[l * 512 + col];
        const float vNh = bnh[l * 512 + col];
        f32x4 accR0 = {vR,vR,vR,vR},   accR1 = {vR,vR,vR,vR};
        f32x4 accZ0 = {vZ,vZ,vZ,vZ},   accZ1 = {vZ,vZ,vZ,vZ};
        f32x4 accN0 = {vNh,vNh,vNh,vNh}, accN1 = {vNh,vNh,vNh,vNh};
        f32x4 giN0  = {vNi,vNi,vNi,vNi}, giN1  = {vNi,vNi,vNi,vNi};

        // gi = x_t @ Wih^T via one zero-padded MFMA per fragment
        {
          short8 ax0 = *(const short8*)(xpack + lane * 8);
          short8 ax1 = *(const short8*)(xpack + 512 + lane * 8);
          const unsigned short* wb = Wip + ((size_t)(l * 96 + ntR) * 64 + lane) * 8;
          short8 bR = *(const short8*)(wb);
          short8 bZ = *(const short8*)(wb + 32 * 64 * 8);
          short8 bN = *(const short8*)(wb + 64 * 64 * 8);
          accR0 = MFMA(ax0, bR, accR0);  accR1 = MFMA(ax1, bR, accR1);
          accZ0 = MFMA(ax0, bZ, accZ0);  accZ1 = MFMA(ax1, bZ, accZ1);
          giN0  = MFMA(ax0, bN, giN0);   giN1  = MFMA(ax1, bN, giN1);
        }

        // K loop: gh = h @ Whh^T (+bhh already in acc)
        const unsigned short* wbR = Wp + ((size_t)(l * 96 + ntR) * 16 * 64 + lane) * 8;
        const unsigned short* hbc = hB[cur];
#pragma unroll 2
        for (int kk = 0; kk < 16; ++kk){
          short8 a0 = *(const short8*)(hbc + aoff0 + kk * 32);
          short8 a1 = *(const short8*)(hbc + aoff1 + kk * 32);
          const unsigned short* w = wbR + (size_t)kk * 512;
          short8 bR = *(const short8*)(w);
          short8 bZ = *(const short8*)(w + 262144);   // +32 N-tiles (z third)
          short8 bN = *(const short8*)(w + 524288);   // +64 N-tiles (n third)
          accR0 = MFMA(a0, bR, accR0);  accR1 = MFMA(a1, bR, accR1);
          accZ0 = MFMA(a0, bZ, accZ0);  accZ1 = MFMA(a1, bZ, accZ1);
          accN0 = MFMA(a0, bN, accN0);  accN1 = MFMA(a1, bN, accN1);
        }

        // gates (registers only; this wave exclusively owns columns [cb, cb+16))
        unsigned short* hbn = hB[cur ^ 1];
#pragma unroll
        for (int m = 0; m < 2; ++m){
          f32x4 aR  = m ? accR1 : accR0;
          f32x4 aZ  = m ? accZ1 : accZ0;
          f32x4 aN4 = m ? accN1 : accN0;
          f32x4 gN  = m ? giN1  : giN0;
#pragma unroll
          for (int q = 0; q < 4; ++q){
            int b = m * 16 + l4 * 4 + q;           // C/D row = (lane>>4)*4 + reg
            float r  = 1.f / (1.f + __expf(-aR[q]));
            float z  = 1.f / (1.f + __expf(-aZ[q]));
            float aN = gN[q] + r * aN4[q];
            float n  = 1.f - 2.f / (1.f + __expf(2.f * aN));
            float ho = hF[b * 528 + col];
            float hn = n + z * (ho - n);           // (1-z)*n + z*h
            hF[b * 528 + col] = hn;
            hbn[b * 536 + col] = f2bf(hn);
          }
        }
      }
      __syncthreads();   // all writes to hB[cur^1] visible; hF column-exclusive
      cur ^= 1;
    }
  }

  for (int i = tid; i < 32 * 512; i += 1024){
    int b = i >> 9, j = i & 511;
    out[((size_t)(b0 + b)) * 512 + j] = hF[b * 528 + j];
  }
}

extern "C" void kernel_launch(void* const* d_in, const int* in_sizes, int n_in,
                              void* d_out, int out_size, void* d_ws, size_t ws_size,
                              hipStream_t stream){
  const float* x   = (const float*)d_in[0];
  const float* Wih = (const float*)d_in[1];
  const float* Whh = (const float*)d_in[2];
  const float* bih = (const float*)d_in[3];
  const float* bhh = (const float*)d_in[4];

  unsigned char* ws = (unsigned char*)d_ws;
  unsigned short* Wp  = (unsigned short*)(ws + OFF_WHH);
  unsigned short* Wip = (unsigned short*)(ws + OFF_WIH);
  float* brz = (float*)(ws + OFF_BRZ);
  float* bni = (float*)(ws + OFF_BNI);
  float* bnh = (float*)(ws + OFF_BNH);

  prep_whh <<<1152, 256, 0, stream>>>(Whh, Wp);
  prep_wih <<<  72, 256, 0, stream>>>(Wih, Wip);
  prep_bias<<<  18, 256, 0, stream>>>(bih, bhh, brz, bni, bnh);
  gru_main <<< 128, 1024, 0, stream>>>(x, Wp, Wip, brz, bni, bnh, (float*)d_out);
}

// Round 2
// 7174.357 us; speedup vs baseline: 1.0335x; 1.0335x over previous
//
#include <hip/hip_runtime.h>

typedef __attribute__((ext_vector_type(8))) short short8;
typedef __attribute__((ext_vector_type(4))) float f32x4;

#define MFMA(a,b,c) __builtin_amdgcn_mfma_f32_16x16x32_bf16(a,b,c,0,0,0)

// Problem dims
#define S_LEN 128
#define IN_D  8
#define HID   512
#define NL    3
#define HSTR  536   // bf16 h row stride (shorts): 16B-aligned rows, 2-way-max read conflicts

// ws layout (bytes)
#define OFF_WHH 0                      // [3][96][16][64][8] bf16 = 4,718,592
#define OFF_WIH (4718592)              // [3][96][64][8] bf16    =   294,912

__device__ __forceinline__ unsigned short f2bf(float f){
  unsigned u = __float_as_uint(f);
  u += 0x7FFFu + ((u >> 16) & 1u);     // round-to-nearest-even
  return (unsigned short)(u >> 16);
}

// Pack Whh [3][1536][512] f32 -> bf16 MFMA B-fragment order:
// idx = (((l*96+nt)*16+kk)*64+lane)*8 + j ; value = Whh[l][nt*16+(lane&15)][kk*32+(lane>>4)*8+j]
__global__ void prep_whh(const float* __restrict__ Whh, unsigned short* __restrict__ Wp){
  int gid = blockIdx.x * 256 + threadIdx.x;     // 294912 total
  int lane = gid & 63;
  int r = gid >> 6;
  int kk = r & 15; r >>= 4;
  int nt = r % 96;
  int l  = r / 96;
  int n  = nt * 16 + (lane & 15);
  int k0 = kk * 32 + (lane >> 4) * 8;
  const float* src = Whh + ((size_t)l * 1536 + n) * 512 + k0;
  unsigned short t[8];
#pragma unroll
  for (int j = 0; j < 8; ++j) t[j] = f2bf(src[j]);
  uint4 v;
  v.x = t[0] | ((unsigned)t[1] << 16);
  v.y = t[2] | ((unsigned)t[3] << 16);
  v.z = t[4] | ((unsigned)t[5] << 16);
  v.w = t[6] | ((unsigned)t[7] << 16);
  *(uint4*)(Wp + (size_t)gid * 8) = v;
}

// Pack Wih [3][1536][8] -> zero-padded (K=8 of 32) B-fragments: only lanes 0..15 nonzero
__global__ void prep_wih(const float* __restrict__ Wih, unsigned short* __restrict__ Wip){
  int gid = blockIdx.x * 256 + threadIdx.x;     // 18432 total
  int lane = gid & 63;
  int r = gid >> 6;
  int nt = r % 96;
  int l  = r / 96;
  unsigned short t[8] = {0,0,0,0,0,0,0,0};
  if ((lane >> 4) == 0){
    int n = nt * 16 + (lane & 15);
    const float* src = Wih + ((size_t)l * 1536 + n) * 8;
#pragma unroll
    for (int j = 0; j < 8; ++j) t[j] = f2bf(src[j]);
  }
  uint4 v;
  v.x = t[0] | ((unsigned)t[1] << 16);
  v.y = t[2] | ((unsigned)t[3] << 16);
  v.z = t[4] | ((unsigned)t[5] << 16);
  v.w = t[6] | ((unsigned)t[7] << 16);
  *(uint4*)(Wip + (size_t)gid * 8) = v;
}

// Main: 128 blocks x 1024 threads. Block owns batch rows [b0, b0+32).
// fp32 h master lives in REGISTERS (same-lane produce/consume property);
// bf16 h double-buffered in LDS for MFMA A-frags (1 barrier per cell-layer).
// Biases staged in LDS (broadcast reads). kk-loop fully unrolled so the
// compiler software-pipelines the L2 weight-fragment loads.
__global__ __launch_bounds__(1024, 1) void gru_main(
    const float* __restrict__ x,
    const unsigned short* __restrict__ Wp,
    const unsigned short* __restrict__ Wip,
    const float* __restrict__ bih,
    const float* __restrict__ bhh,
    float* __restrict__ out)
{
  __shared__ __align__(16) unsigned short hB[2][32 * HSTR];  // bf16 h, double buffer
  __shared__ __align__(16) unsigned short xpack[2][1024];    // x_t A-frags, t-parity buffers
  __shared__ float sBrz[3 * 1024];                           // bih+bhh for r,z
  __shared__ float sBni[3 * 512];                            // bih (n)
  __shared__ float sBnh[3 * 512];                            // bhh (n)

  const int tid  = threadIdx.x;
  const int wv   = tid >> 6;
  const int lane = tid & 63;
  const int l15  = lane & 15;
  const int l4   = lane >> 4;
  const int b0   = blockIdx.x * 32;

  for (int i = tid; i < 32 * HSTR; i += 1024){ hB[0][i] = 0; hB[1][i] = 0; }
  for (int i = tid; i < 3072; i += 1024){
    int l = i >> 10, c = i & 1023;
    sBrz[i] = bih[l * 1536 + c] + bhh[l * 1536 + c];
  }
  for (int i = tid; i < 1536; i += 1024){
    int l = i >> 9, c = i & 511;
    sBni[i] = bih[l * 1536 + 1024 + c];
    sBnh[i] = bhh[l * 1536 + 1024 + c];
  }

  // fp32 h master in registers: [p][m][q] -> batch row m*16+l4*4+q, col wv*32+p*16+l15
  float hreg[2][2][4];
#pragma unroll
  for (int p = 0; p < 2; ++p)
#pragma unroll
    for (int m = 0; m < 2; ++m)
#pragma unroll
      for (int q = 0; q < 4; ++q) hreg[p][m][q] = 0.f;

  // xpack writer mapping: tid = (m*64+lane)*8 + j
  const int xm = tid >> 9, xl = (tid >> 3) & 63, xj = tid & 7;
  const size_t xbase = ((size_t)(b0 + xm * 16 + (xl & 15))) * (S_LEN * IN_D) + xj;
  const int xvalid = (xl < 16);

  const int aoff0 = l15 * HSTR + l4 * 8;          // A-frag m=0 (rows 0..15)
  const int aoff1 = aoff0 + 16 * HSTR;            // A-frag m=1 (rows 16..31)

  int cur = 0;
  for (int t = 0; t < S_LEN; ++t){
    { // stage x_t fragment into parity buffer (no extra barrier needed)
      float xv = xvalid ? x[xbase + (size_t)t * IN_D] : 0.f;
      xpack[t & 1][tid] = f2bf(xv);
    }
    const unsigned short* xp = &xpack[t & 1][0];

    for (int l = 0; l < NL; ++l){
      __syncthreads();   // makes prev layer's hB writes (and this t's xpack) visible
      const unsigned short* hbc = hB[cur];
      unsigned short*       hbn = hB[cur ^ 1];
#pragma unroll
      for (int p = 0; p < 2; ++p){
        const int cb  = wv * 32 + p * 16;        // output column base (0..511)
        const int ntR = cb >> 4;                 // N-tile index within gate third
        const int col = cb + l15;

        const float vR  = sBrz[l * 1024 + col];
        const float vZ  = sBrz[l * 1024 + 512 + col];
        const float vNi = sBni[l * 512 + col];
        const float vNh = sBnh[l * 512 + col];
        f32x4 accR0 = {vR,vR,vR,vR},     accR1 = {vR,vR,vR,vR};
        f32x4 accZ0 = {vZ,vZ,vZ,vZ},     accZ1 = {vZ,vZ,vZ,vZ};
        f32x4 accN0 = {vNh,vNh,vNh,vNh}, accN1 = {vNh,vNh,vNh,vNh};
        f32x4 giN0  = {vNi,vNi,vNi,vNi}, giN1  = {vNi,vNi,vNi,vNi};

        // gi = x_t @ Wih^T via one zero-padded MFMA per fragment
        {
          short8 ax0 = *(const short8*)(xp + lane * 8);
          short8 ax1 = *(const short8*)(xp + 512 + lane * 8);
          const unsigned short* wb = Wip + ((size_t)(l * 96 + ntR) * 64 + lane) * 8;
          short8 bR = *(const short8*)(wb);
          short8 bZ = *(const short8*)(wb + 32 * 64 * 8);
          short8 bN = *(const short8*)(wb + 64 * 64 * 8);
          accR0 = MFMA(ax0, bR, accR0);  accR1 = MFMA(ax1, bR, accR1);
          accZ0 = MFMA(ax0, bZ, accZ0);  accZ1 = MFMA(ax1, bZ, accZ1);
          giN0  = MFMA(ax0, bN, giN0);   giN1  = MFMA(ax1, bN, giN1);
        }

        // K loop: gh = h @ Whh^T (+bhh already in acc). Full unroll -> deep load pipeline.
        const unsigned short* wbR = Wp + ((size_t)(l * 96 + ntR) * 16 * 64 + lane) * 8;
#pragma unroll
        for (int kk = 0; kk < 16; ++kk){
          short8 a0 = *(const short8*)(hbc + aoff0 + kk * 32);
          short8 a1 = *(const short8*)(hbc + aoff1 + kk * 32);
          const unsigned short* w = wbR + (size_t)kk * 512;
          short8 bR = *(const short8*)(w);
          short8 bZ = *(const short8*)(w + 262144);   // z third (+32 N-tiles)
          short8 bN = *(const short8*)(w + 524288);   // n third (+64 N-tiles)
          accR0 = MFMA(a0, bR, accR0);  accR1 = MFMA(a1, bR, accR1);
          accZ0 = MFMA(a0, bZ, accZ0);  accZ1 = MFMA(a1, bZ, accZ1);
          accN0 = MFMA(a0, bN, accN0);  accN1 = MFMA(a1, bN, accN1);
        }

        // gates: registers only; h master in hreg (same-lane RAW across cells/layers)
#pragma unroll
        for (int m = 0; m < 2; ++m){
          f32x4 aR  = m ? accR1 : accR0;
          f32x4 aZ  = m ? accZ1 : accZ0;
          f32x4 aN4 = m ? accN1 : accN0;
          f32x4 gN  = m ? giN1  : giN0;
#pragma unroll
          for (int q = 0; q < 4; ++q){
            int b = m * 16 + l4 * 4 + q;           // batch row within tile
            float r  = 1.f / (1.f + __expf(-aR[q]));
            float z  = 1.f / (1.f + __expf(-aZ[q]));
            float aN = gN[q] + r * aN4[q];
            float n  = 1.f - 2.f / (1.f + __expf(2.f * aN));
            float hn = n + z * (hreg[p][m][q] - n);  // (1-z)*n + z*h
            hreg[p][m][q] = hn;
            hbn[b * HSTR + col] = f2bf(hn);
          }
        }
      }
      cur ^= 1;
    }
  }

  // epilogue: h master is already in registers
#pragma unroll
  for (int p = 0; p < 2; ++p)
#pragma unroll
    for (int m = 0; m < 2; ++m)
#pragma unroll
      for (int q = 0; q < 4; ++q){
        int b   = m * 16 + l4 * 4 + q;
        int col = wv * 32 + p * 16 + l15;
        out[((size_t)(b0 + b)) * 512 + col] = hreg[p][m][q];
      }
}

extern "C" void kernel_launch(void* const* d_in, const int* in_sizes, int n_in,
                              void* d_out, int out_size, void* d_ws, size_t ws_size,
                              hipStream_t stream){
  const float* x   = (const float*)d_in[0];
  const float* Wih = (const float*)d_in[1];
  const float* Whh = (const float*)d_in[2];
  const float* bih = (const float*)d_in[3];
  const float* bhh = (const float*)d_in[4];

  unsigned char* ws = (unsigned char*)d_ws;
  unsigned short* Wp  = (unsigned short*)(ws + OFF_WHH);
  unsigned short* Wip = (unsigned short*)(ws + OFF_WIH);

  prep_whh <<<1152, 256, 0, stream>>>(Whh, Wp);
  prep_wih <<<  72, 256, 0, stream>>>(Wih, Wip);
  gru_main <<< 128, 1024, 0, stream>>>(x, Wp, Wip, bih, bhh, (float*)d_out);
}